// Round 4
// baseline (89.541 us; speedup 1.0000x reference)
//
#include <hip/hip_runtime.h>
#include <math.h>

#define C_IN 2048
#define N_EXP 64
#define TPB 16            // tokens per block
#define BK 64             // K per round
#define NCH (C_IN / BK)   // 32 rounds
#define DELTA  3e-4f      // risky-gap threshold (>=100x expected logit error)
#define DELTA2 1e-3f      // candidate window around v2

typedef __bf16 bf16x8 __attribute__((ext_vector_type(8)));
typedef float f32x4 __attribute__((ext_vector_type(4)));

__device__ __forceinline__ void cvt_split(float f, ushort& h, ushort& l) {
    uint u = __float_as_uint(f);
    uint hr = (u + (0x7FFFu + ((u >> 16) & 1u))) >> 16;
    h = (ushort)hr;
    float hf = __uint_as_float(hr << 16);
    uint v = __float_as_uint(f - hf);
    l = (ushort)((v + (0x7FFFu + ((v >> 16) & 1u))) >> 16);
}

// Pre-kernel: W fp32 [64][2048] -> wh bf16 + wl bf16 (residual), 512 KB.
__global__ void conv_w_kernel(const float* __restrict__ W,
                              ushort* __restrict__ wh, ushort* __restrict__ wl) {
    int i = blockIdx.x * 256 + threadIdx.x;   // 512*256 = 131072 elems
    float f = W[i];
    ushort h, lo;
    cvt_split(f, h, lo);
    wh[i] = h;
    wl[i] = lo;
}

// Main: 128 thr (2 waves), 16 tokens/block, grid 1024 -> 4 blocks/CU
// (4 independent barrier domains). Split-bf16 MFMA:
// logits = xh*wh + xl*wh + xh*wl (xl*wl dropped, ~2e-6).
// x: global->reg (2 rounds deep) ->convert-> LDS (XOR unit-swizzle), dbuf.
// W: bf16 hi/lo fetched as B-fragments DIRECTLY from global (L1/L2-resident,
//    perfectly coalesced: lanes {l,l+16,l+32,l+48} cover one expert row's
//    64 contiguous bytes), prefetched 1 round ahead into registers.
// Wave w: 16 tokens x 32 experts (2 N-frags). Per round: 4 ds_read_b128,
// 8 global 16B W loads, 12 MFMA, 1 barrier.
// Epilogue: part-transpose via LDS (stride 65), wave-per-8-tokens softmax +
// top-2 with exact-fp32 repair for tokens whose top gaps are < DELTA.
__global__ __launch_bounds__(128, 2) void topk_gate_kernel(
    const float* __restrict__ x, const float* __restrict__ Wf,
    const float* __restrict__ b, const ushort* __restrict__ wh_g,
    const ushort* __restrict__ wl_g, float* __restrict__ out)
{
    __shared__ __align__(16) ushort smem[4096];   // 8 KB: XH[2][16][64], XL[2][16][64]
    // XH(buf) = smem + buf*1024 ; XL(buf) = smem + 2048 + buf*1024

    const int tid = threadIdx.x;
    const int w = tid >> 6, l = tid & 63;
    const int tokBase = blockIdx.x * TPB;

    // staging roles: row = tid>>3 (0..15), c = tid&7; thread's k = c*4 + 32m
    const int xrow = tid >> 3, xc = tid & 7;
    const float* xg = x + (size_t)tokBase * C_IN;

    // A-frag LDS elem offsets (ushort units), swizzle u ^= row&7
    const int arow = l & 15, kg = l >> 4;
    int aoff[2];
#pragma unroll
    for (int kt = 0; kt < 2; ++kt)
        aoff[kt] = arow * 64 + (((kt * 4 + kg) ^ (arow & 7)) * 8);

    // W global elem offsets: expert e = w*32 + eg*16 + (l&15)
    int woff[2][2];
#pragma unroll
    for (int eg = 0; eg < 2; ++eg)
#pragma unroll
    for (int kt = 0; kt < 2; ++kt)
        woff[eg][kt] = (w * 32 + eg * 16 + arow) * C_IN + kt * 32 + kg * 8;

    f32x4 acc[2] = {{0.f,0.f,0.f,0.f},{0.f,0.f,0.f,0.f}};
    float4 xA[2], xB[2];
    uint4 wA[8], wB[8];

#define STAGE(XV, RND) do {                                                   \
    ushort* dh = smem + ((RND) & 1) * 1024;                                   \
    ushort* dl = smem + 2048 + ((RND) & 1) * 1024;                            \
    _Pragma("unroll") for (int m = 0; m < 2; ++m) {                           \
        ushort h_[4], lo_[4];                                                 \
        cvt_split(XV[m].x, h_[0], lo_[0]); cvt_split(XV[m].y, h_[1], lo_[1]); \
        cvt_split(XV[m].z, h_[2], lo_[2]); cvt_split(XV[m].w, h_[3], lo_[3]); \
        uint2 hv = {(uint)h_[0] | ((uint)h_[1] << 16),                        \
                    (uint)h_[2] | ((uint)h_[3] << 16)};                       \
        uint2 lv = {(uint)lo_[0] | ((uint)lo_[1] << 16),                      \
                    (uint)lo_[2] | ((uint)lo_[3] << 16)};                     \
        const int u_ = (4 * m + (xc >> 1)) ^ (xrow & 7);                      \
        const int el_ = xrow * 64 + u_ * 8 + (xc & 1) * 4;                    \
        *(uint2*)&dh[el_] = hv; *(uint2*)&dl[el_] = lv;                       \
    } } while (0)

#define ROUND(R, XLD, XCV, WU, WLD) do {                                      \
    if ((R) + 2 < NCH) {                                                      \
        const int kk = ((R) + 2) * BK;                                        \
        _Pragma("unroll") for (int m = 0; m < 2; ++m)                         \
            XLD[m] = *(const float4*)(xg + (size_t)xrow * C_IN + kk + xc * 4 + 32 * m); \
    }                                                                         \
    if ((R) + 1 < NCH) {                                                      \
        const int kw = ((R) + 1) * BK;                                        \
        _Pragma("unroll") for (int eg = 0; eg < 2; ++eg)                      \
        _Pragma("unroll") for (int kt = 0; kt < 2; ++kt) {                    \
            WLD[eg * 4 + kt * 2 + 0] = *(const uint4*)(wh_g + woff[eg][kt] + kw); \
            WLD[eg * 4 + kt * 2 + 1] = *(const uint4*)(wl_g + woff[eg][kt] + kw); \
        }                                                                     \
    }                                                                         \
    {                                                                         \
        const ushort* xh = smem + ((R) & 1) * 1024;                           \
        const ushort* xl = smem + 2048 + ((R) & 1) * 1024;                    \
        _Pragma("unroll") for (int kt = 0; kt < 2; ++kt) {                    \
            bf16x8 ah = __builtin_bit_cast(bf16x8, *(const uint4*)&xh[aoff[kt]]); \
            bf16x8 al = __builtin_bit_cast(bf16x8, *(const uint4*)&xl[aoff[kt]]); \
            _Pragma("unroll") for (int eg = 0; eg < 2; ++eg) {                \
                bf16x8 bh = __builtin_bit_cast(bf16x8, WU[eg * 4 + kt * 2 + 0]); \
                bf16x8 bl = __builtin_bit_cast(bf16x8, WU[eg * 4 + kt * 2 + 1]); \
                acc[eg] = __builtin_amdgcn_mfma_f32_16x16x32_bf16(ah, bh, acc[eg], 0, 0, 0); \
                acc[eg] = __builtin_amdgcn_mfma_f32_16x16x32_bf16(al, bh, acc[eg], 0, 0, 0); \
                acc[eg] = __builtin_amdgcn_mfma_f32_16x16x32_bf16(ah, bl, acc[eg], 0, 0, 0); \
            }                                                                 \
        }                                                                     \
    }                                                                         \
    if ((R) + 1 < NCH) STAGE(XCV, (R) + 1);                                   \
    __syncthreads();                                                          \
    } while (0)

    // ---- prologue: x r0 (temp) + x r1 (xB) + W r0 (wA); stage r0; barrier
    {
        float4 p[2];
#pragma unroll
        for (int m = 0; m < 2; ++m)
            p[m] = *(const float4*)(xg + (size_t)xrow * C_IN + xc * 4 + 32 * m);
#pragma unroll
        for (int m = 0; m < 2; ++m)
            xB[m] = *(const float4*)(xg + (size_t)xrow * C_IN + BK + xc * 4 + 32 * m);
#pragma unroll
        for (int eg = 0; eg < 2; ++eg)
#pragma unroll
        for (int kt = 0; kt < 2; ++kt) {
            wA[eg * 4 + kt * 2 + 0] = *(const uint4*)(wh_g + woff[eg][kt]);
            wA[eg * 4 + kt * 2 + 1] = *(const uint4*)(wl_g + woff[eg][kt]);
        }
        STAGE(p, 0);
        __syncthreads();
    }

    for (int rp = 0; rp < NCH / 2; ++rp) {
        const int r0 = 2 * rp;
        ROUND(r0, xA, xB, wA, wB);
        ROUND(r0 + 1, xB, xA, wB, wA);
    }

    // ---- epilogue: part transpose (stride 65 kills store conflicts) ----
    float* part = (float*)smem;   // [16][65] fp32 = 4160 B (fits 8 KB)
#pragma unroll
    for (int eg = 0; eg < 2; ++eg)
#pragma unroll
    for (int r2 = 0; r2 < 4; ++r2)
        part[(kg * 4 + r2) * 65 + w * 32 + eg * 16 + arow] = acc[eg][r2];
    __syncthreads();

    const int e = l;
    const float be = b[e];
    for (int ti = 0; ti < 8; ++ti) {
        const int t = w * 8 + ti;
        float logit = part[t * 65 + e] + be;

        float v1, v2, v3; int i1, i2;
        for (int pass = 0; pass < 2; ++pass) {
            v1 = logit; i1 = e;
#pragma unroll
            for (int off = 32; off >= 1; off >>= 1) {
                float ov = __shfl_xor(v1, off, 64);
                int   oi = __shfl_xor(i1, off, 64);
                if (ov > v1 || (ov == v1 && oi < i1)) { v1 = ov; i1 = oi; }
            }
            v2 = (e == i1) ? -3.4e38f : logit;
            i2 = (e == i1) ? N_EXP : e;
#pragma unroll
            for (int off = 32; off >= 1; off >>= 1) {
                float ov = __shfl_xor(v2, off, 64);
                int   oi = __shfl_xor(i2, off, 64);
                if (ov > v2 || (ov == v2 && oi < i2)) { v2 = ov; i2 = oi; }
            }
            v3 = (e == i1 || e == i2) ? -3.4e38f : logit;
#pragma unroll
            for (int off = 32; off >= 1; off >>= 1) {
                float ov = __shfl_xor(v3, off, 64);
                v3 = (ov > v3) ? ov : v3;
            }
            if (pass == 1) break;
            const bool risky = (v1 - v2 < DELTA) || (v2 - v3 < DELTA);
            if (!risky) break;
            // exact fp32 recompute of candidate experts (wave-uniform path)
            unsigned long long cm = __ballot(logit >= v2 - DELTA2);
            const float* xr = x + (size_t)(tokBase + t) * C_IN;
            while (cm) {
                const int ce = __ffsll((unsigned long long)cm) - 1;
                cm &= cm - 1;
                const float* wr = Wf + (size_t)ce * C_IN;
                float p = 0.f;
#pragma unroll 8
                for (int i = 0; i < 32; ++i)
                    p = fmaf(xr[l + 64 * i], wr[l + 64 * i], p);
#pragma unroll
                for (int off = 32; off >= 1; off >>= 1)
                    p += __shfl_xor(p, off, 64);
                if (e == ce) logit = p + be;
            }
        }

        float ex = expf(logit - v1);
        float ssum = ex;
#pragma unroll
        for (int off = 32; off >= 1; off >>= 1)
            ssum += __shfl_xor(ssum, off, 64);
        const float inv = 1.0f / ssum;
        const float p1 = inv;
        const float p2 = expf(v2 - v1) * inv;
        const float o = (e == i1) ? p1 : ((e == i2) ? p2 : 0.0f);
        out[(size_t)(tokBase + t) * N_EXP + e] = o;
    }
#undef ROUND
#undef STAGE
}

extern "C" void kernel_launch(void* const* d_in, const int* in_sizes, int n_in,
                              void* d_out, int out_size, void* d_ws, size_t ws_size,
                              hipStream_t stream) {
    const float* x = (const float*)d_in[0];   // [4,4096,2048]
    const float* W = (const float*)d_in[1];   // [64,2048]
    const float* b = (const float*)d_in[2];   // [64]
    float* out = (float*)d_out;               // [4,4096,64]

    ushort* wh = (ushort*)d_ws;               // [64][2048] bf16 hi
    ushort* wl = wh + N_EXP * C_IN;           // [64][2048] bf16 lo

    conv_w_kernel<<<512, 256, 0, stream>>>(W, wh, wl);

    const int tokens = in_sizes[0] / C_IN;    // 16384
    const int grid = tokens / TPB;            // 1024
    topk_gate_kernel<<<grid, 128, 0, stream>>>(x, W, b, wh, wl, out);
}

// Round 5
// 56.732 us; speedup vs baseline: 1.5783x; 1.5783x over previous
//
#include <hip/hip_runtime.h>
#include <math.h>

#define C_IN 2048
#define N_EXP 64
#define TPB 32            // tokens per block (all 4 waves share them)
#define CHUNK 64          // k per chunk
#define KWIN 512          // per-wave k-window (in-block k-split by 4)
#define NCHUNK 8          // KWIN / CHUNK
#define DELTA  3e-4f      // risky-gap threshold (>=100x expected logit error)
#define DELTA2 1e-3f      // candidate window around v2

typedef __bf16 bf16x8 __attribute__((ext_vector_type(8)));
typedef float f32x4 __attribute__((ext_vector_type(4)));

__device__ __forceinline__ void cvt_split(float f, ushort& h, ushort& l) {
    uint u = __float_as_uint(f);
    uint hr = (u + (0x7FFFu + ((u >> 16) & 1u))) >> 16;
    h = (ushort)hr;
    float hf = __uint_as_float(hr << 16);
    uint v = __float_as_uint(f - hf);
    l = (ushort)((v + (0x7FFFu + ((v >> 16) & 1u))) >> 16);
}

// W [64][2048] fp32 -> frag-major bf16 hi/lo (256 KB each):
// o = (eg*64 + ks)*512 + lane*8 + j  <->  e = eg*16+(lane&15), k = ks*32+(lane>>4)*8+j
// so kernel A's W-fragment load is ONE fully-contiguous 1-KB wave load.
__global__ void conv_w_kernel(const float* __restrict__ W,
                              ushort* __restrict__ whf, ushort* __restrict__ wlf) {
    const int o = blockIdx.x * 256 + threadIdx.x;   // 0..131071
    const int egks = o >> 9;
    const int lane = (o >> 3) & 63;
    const int j = o & 7;
    const int e = (egks >> 6) * 16 + (lane & 15);
    const int k = (egks & 63) * 32 + (lane >> 4) * 8 + j;
    ushort h, lo;
    cvt_split(W[e * C_IN + k], h, lo);
    whf[o] = h;
    wlf[o] = lo;
}

// Main: 512 blocks x 256 thr (4 waves). NO barriers in the hot loop.
// Wave wv: 32 tokens x 64 experts x k-window [wv*512, wv*512+512).
// Per 64-k chunk: 8 x-loads (4-segment coalesced, 2 chunks deep) -> cvt to
// bf16 hi/lo -> wave-private single LDS buffer (in-order DS => no sync needed)
// -> 8 ds_read_b128 frags; W hi/lo frags direct from L2 (frag-major, 1-KB
// coalesced wave loads, 1 kstep ahead); 48 MFMA. End: partials to own LDS,
// ONE __syncthreads, cross-wave reduce + softmax/top-2 + fp32 repair.
__global__ __launch_bounds__(256, 2) void topk_gate_kernel(
    const float* __restrict__ x, const float* __restrict__ Wf,
    const float* __restrict__ b, const ushort* __restrict__ whf,
    const ushort* __restrict__ wlf, float* __restrict__ out)
{
    __shared__ __align__(16) ushort lds[4][4096];   // 8 KB per wave

    const int tid = threadIdx.x;
    const int wv = tid >> 6, l = tid & 63;
    const int t0 = blockIdx.x * TPB;
    const int row_l = l >> 4;      // 0..3
    const int kc = l & 15;

    ushort* hbuf = lds[wv];            // [32][64] bf16 hi, XOR-swizzled
    ushort* lbuf = lds[wv] + 2048;     // lo

    const float* xg = x + (size_t)t0 * C_IN + wv * KWIN;

    // LDS write offsets (ushort units): row r=m*4+row_l, 4 k-floats at kc*4,
    // swizzle: k-group XOR (r&3)*16 ushorts (=32 B)
    int xwoff[8];
#pragma unroll
    for (int m = 0; m < 8; ++m)
        xwoff[m] = (m * 4 + row_l) * 64 + ((kc * 4) ^ (row_l * 16));

    // A-frag read offsets: row ar=mf*16+(l&15), k = ks*32+(l>>4)*8, same XOR
    int aoff[2][2];
#pragma unroll
    for (int mf = 0; mf < 2; ++mf)
#pragma unroll
    for (int ks = 0; ks < 2; ++ks) {
        const int ar = mf * 16 + (l & 15);
        aoff[mf][ks] = ar * 64 + ((ks * 32 + (l >> 4) * 8) ^ ((ar & 3) * 16));
    }

    f32x4 acc[2][4];
#pragma unroll
    for (int mf = 0; mf < 2; ++mf)
#pragma unroll
    for (int eg = 0; eg < 4; ++eg)
        acc[mf][eg] = (f32x4){0.f, 0.f, 0.f, 0.f};

    float4 xvA[8], xvB[8];
    uint4 wWA[8], wWB[8];

    auto LOADX = [&](float4* dst, int c) {
#pragma unroll
        for (int m = 0; m < 8; ++m)
            dst[m] = *(const float4*)(xg + (size_t)(m * 4 + row_l) * C_IN + c * CHUNK + kc * 4);
    };
    auto LOADW = [&](uint4* dst, int c, int ks) {
        const int ksa = wv * 16 + c * 2 + ks;
#pragma unroll
        for (int eg = 0; eg < 4; ++eg) {
            const int base = (eg * 64 + ksa) * 512 + l * 8;
            dst[eg * 2 + 0] = *(const uint4*)&whf[base];
            dst[eg * 2 + 1] = *(const uint4*)&wlf[base];
        }
    };
    auto CVTWR = [&](const float4* src) {
#pragma unroll
        for (int m = 0; m < 8; ++m) {
            ushort h0, h1, h2, h3, q0, q1, q2, q3;
            cvt_split(src[m].x, h0, q0); cvt_split(src[m].y, h1, q1);
            cvt_split(src[m].z, h2, q2); cvt_split(src[m].w, h3, q3);
            uint2 hv = {(uint)h0 | ((uint)h1 << 16), (uint)h2 | ((uint)h3 << 16)};
            uint2 lv = {(uint)q0 | ((uint)q1 << 16), (uint)q2 | ((uint)q3 << 16)};
            *(uint2*)&hbuf[xwoff[m]] = hv;
            *(uint2*)&lbuf[xwoff[m]] = lv;
        }
    };
    auto FRAGMFMA = [&](int ks, const uint4* wbuf) {
#pragma unroll
        for (int mf = 0; mf < 2; ++mf) {
            bf16x8 ah = __builtin_bit_cast(bf16x8, *(const uint4*)&hbuf[aoff[mf][ks]]);
            bf16x8 al = __builtin_bit_cast(bf16x8, *(const uint4*)&lbuf[aoff[mf][ks]]);
#pragma unroll
            for (int eg = 0; eg < 4; ++eg) {
                bf16x8 bh = __builtin_bit_cast(bf16x8, wbuf[eg * 2 + 0]);
                bf16x8 bl = __builtin_bit_cast(bf16x8, wbuf[eg * 2 + 1]);
                acc[mf][eg] = __builtin_amdgcn_mfma_f32_16x16x32_bf16(ah, bh, acc[mf][eg], 0, 0, 0);
                acc[mf][eg] = __builtin_amdgcn_mfma_f32_16x16x32_bf16(al, bh, acc[mf][eg], 0, 0, 0);
                acc[mf][eg] = __builtin_amdgcn_mfma_f32_16x16x32_bf16(ah, bl, acc[mf][eg], 0, 0, 0);
            }
        }
    };

    // prologue: x 2 chunks deep, W one kstep ahead
    LOADX(xvA, 0);
    LOADX(xvB, 1);
    LOADW(wWA, 0, 0);

#pragma unroll
    for (int cc = 0; cc < NCHUNK; cc += 2) {
        // chunk cc (from xvA)
        LOADW(wWB, cc, 1);                       // in flight under cvt
        CVTWR(xvA);
        if (cc + 2 < NCHUNK) LOADX(xvA, cc + 2);
        FRAGMFMA(0, wWA);
        LOADW(wWA, cc + 1, 0);
        FRAGMFMA(1, wWB);
        // chunk cc+1 (from xvB)
        LOADW(wWB, cc + 1, 1);
        CVTWR(xvB);
        if (cc + 3 < NCHUNK) LOADX(xvB, cc + 3);
        FRAGMFMA(0, wWA);
        if (cc + 2 < NCHUNK) LOADW(wWA, cc + 2, 0);
        FRAGMFMA(1, wWB);
    }

    // ---- partials to own LDS buffer (reuse; in-order DS, no sync needed) ----
    float* fb = (float*)lds[wv];   // [32 tokens][64 experts] fp32 = 8 KB
#pragma unroll
    for (int mf = 0; mf < 2; ++mf)
#pragma unroll
    for (int eg = 0; eg < 4; ++eg)
#pragma unroll
    for (int r = 0; r < 4; ++r)
        fb[(mf * 16 + (l >> 4) * 4 + r) * 64 + eg * 16 + (l & 15)] = acc[mf][eg][r];

    __syncthreads();   // the ONLY barrier

    // ---- cross-wave reduce + softmax/top-2 (wave wv: tokens wv*8..wv*8+7) ----
    const float* f0 = (const float*)lds[0];
    const float* f1 = (const float*)lds[1];
    const float* f2 = (const float*)lds[2];
    const float* f3 = (const float*)lds[3];
    const int e = l;
    const float be = b[e];

    for (int ti = 0; ti < 8; ++ti) {
        const int t = wv * 8 + ti;
        float logit = f0[t * 64 + e] + f1[t * 64 + e]
                    + f2[t * 64 + e] + f3[t * 64 + e] + be;

        float v1, v2, v3; int i1, i2;
        for (int pass = 0; pass < 2; ++pass) {
            v1 = logit; i1 = e;
#pragma unroll
            for (int off = 32; off >= 1; off >>= 1) {
                float ov = __shfl_xor(v1, off, 64);
                int   oi = __shfl_xor(i1, off, 64);
                if (ov > v1 || (ov == v1 && oi < i1)) { v1 = ov; i1 = oi; }
            }
            v2 = (e == i1) ? -3.4e38f : logit;
            i2 = (e == i1) ? N_EXP : e;
#pragma unroll
            for (int off = 32; off >= 1; off >>= 1) {
                float ov = __shfl_xor(v2, off, 64);
                int   oi = __shfl_xor(i2, off, 64);
                if (ov > v2 || (ov == v2 && oi < i2)) { v2 = ov; i2 = oi; }
            }
            v3 = (e == i1 || e == i2) ? -3.4e38f : logit;
#pragma unroll
            for (int off = 32; off >= 1; off >>= 1) {
                float ov = __shfl_xor(v3, off, 64);
                v3 = (ov > v3) ? ov : v3;
            }
            if (pass == 1) break;
            const bool risky = (v1 - v2 < DELTA) || (v2 - v3 < DELTA);
            if (!risky) break;
            // exact fp32 recompute of candidate experts (wave-uniform path)
            unsigned long long cm = __ballot(logit >= v2 - DELTA2);
            const float* xr = x + (size_t)(t0 + t) * C_IN;
            while (cm) {
                const int ce = __ffsll((unsigned long long)cm) - 1;
                cm &= cm - 1;
                const float* wr = Wf + (size_t)ce * C_IN;
                float p = 0.f;
#pragma unroll 8
                for (int i = 0; i < 32; ++i)
                    p = fmaf(xr[l + 64 * i], wr[l + 64 * i], p);
#pragma unroll
                for (int off = 32; off >= 1; off >>= 1)
                    p += __shfl_xor(p, off, 64);
                if (e == ce) logit = p + be;
            }
        }

        float ex = expf(logit - v1);
        float ssum = ex;
#pragma unroll
        for (int off = 32; off >= 1; off >>= 1)
            ssum += __shfl_xor(ssum, off, 64);
        const float inv = 1.0f / ssum;
        const float p1 = inv;
        const float p2 = expf(v2 - v1) * inv;
        const float o = (e == i1) ? p1 : ((e == i2) ? p2 : 0.0f);
        out[(size_t)(t0 + t) * N_EXP + e] = o;
    }
}

extern "C" void kernel_launch(void* const* d_in, const int* in_sizes, int n_in,
                              void* d_out, int out_size, void* d_ws, size_t ws_size,
                              hipStream_t stream) {
    const float* x = (const float*)d_in[0];   // [4,4096,2048]
    const float* W = (const float*)d_in[1];   // [64,2048]
    const float* b = (const float*)d_in[2];   // [64]
    float* out = (float*)d_out;               // [4,4096,64]

    ushort* whf = (ushort*)d_ws;              // frag-major bf16 hi, 256 KB
    ushort* wlf = whf + N_EXP * C_IN;         // frag-major bf16 lo, 256 KB

    conv_w_kernel<<<512, 256, 0, stream>>>(W, whf, wlf);

    const int tokens = in_sizes[0] / C_IN;    // 16384
    const int grid = tokens / TPB;            // 512
    topk_gate_kernel<<<grid, 256, 0, stream>>>(x, W, b, whf, wlf, out);
}

// Round 6
// 56.468 us; speedup vs baseline: 1.5857x; 1.0047x over previous
//
#include <hip/hip_runtime.h>
#include <math.h>

#define C_IN 2048
#define N_EXP 64
#define TPB 16            // tokens per block (shared by all 4 waves)
#define KWIN 512          // per-wave K window (in-block K-split by 4)
#define KSTEPS 16         // KWIN / 32
#define DELTA  3e-4f      // risky-gap threshold (>=100x expected logit error)
#define DELTA2 1e-3f      // candidate window around v2

typedef __bf16 bf16x8 __attribute__((ext_vector_type(8)));
typedef float f32x4 __attribute__((ext_vector_type(4)));

__device__ __forceinline__ void cvt_split(float f, ushort& h, ushort& l) {
    uint u = __float_as_uint(f);
    uint hr = (u + (0x7FFFu + ((u >> 16) & 1u))) >> 16;
    h = (ushort)hr;
    float hf = __uint_as_float(hr << 16);
    uint v = __float_as_uint(f - hf);
    l = (ushort)((v + (0x7FFFu + ((v >> 16) & 1u))) >> 16);
}

// W [64][2048] fp32 -> frag-major bf16 hi/lo (256 KB each):
// o = (eg*64 + ks)*512 + lane*8 + j  <->  e = eg*16+(lane&15), k = ks*32+(lane>>4)*8+j
// so the main kernel's W-fragment load is ONE fully-contiguous 1-KB wave load.
__global__ void conv_w_kernel(const float* __restrict__ W,
                              ushort* __restrict__ whf, ushort* __restrict__ wlf) {
    const int o = blockIdx.x * 256 + threadIdx.x;   // 0..131071
    const int egks = o >> 9;
    const int lane = (o >> 3) & 63;
    const int j = o & 7;
    const int e = (egks >> 6) * 16 + (lane & 15);
    const int k = (egks & 63) * 32 + (lane >> 4) * 8 + j;
    ushort h, lo;
    cvt_split(W[e * C_IN + k], h, lo);
    whf[o] = h;
    wlf[o] = lo;
}

// Main: 1024 blocks x 256 thr (4 waves) -> 4096 waves = 16 waves/CU (TLP-first).
// Wave wv: 16 tokens x 64 experts x K in [wv*512, wv*512+512). No LDS staging,
// NO barriers in the hot loop: A-fragments read DIRECTLY from global in MFMA
// layout (lane l: token row l&15, k-bytes (l>>4)*32..+32 -> 2 float4), W hi/lo
// read frag-major (contiguous 1-KB wave loads, L2-resident). Split-bf16:
// logit = xh*wh + xl*wh + xh*wl. Per kstep: 2+8 global loads, 8 cvt_split,
// 12 MFMA. End: partials to LDS, ONE __syncthreads, 4-way K-reduce + softmax
// + top-2 + exact-fp32 repair for near-tie tokens.
__global__ __launch_bounds__(256, 4) void topk_gate_kernel(
    const float* __restrict__ x, const float* __restrict__ Wf,
    const float* __restrict__ b, const ushort* __restrict__ whf,
    const ushort* __restrict__ wlf, float* __restrict__ out)
{
    __shared__ float part[4][TPB][65];   // 16.25 KB; stride 65 spreads banks

    const int tid = threadIdx.x;
    const int wv = tid >> 6, l = tid & 63;
    const int t0 = blockIdx.x * TPB;
    const int tr = l & 15;        // token row within A-frag
    const int kg = l >> 4;        // k-group 0..3

    const float* xg = x + (size_t)(t0 + tr) * C_IN + wv * KWIN + kg * 8;

    f32x4 acc[4];
#pragma unroll
    for (int eg = 0; eg < 4; ++eg) acc[eg] = (f32x4){0.f, 0.f, 0.f, 0.f};

#pragma unroll 2
    for (int ks = 0; ks < KSTEPS; ++ks) {
        // A-fragment direct from global (fp32): 8 consecutive floats/lane
        const float4 a0 = *(const float4*)(xg + ks * 32);
        const float4 a1 = *(const float4*)(xg + ks * 32 + 4);
        // W-fragments, frag-major (contiguous per wave)
        const int ksa = wv * KSTEPS + ks;
        uint4 wb[8];
#pragma unroll
        for (int eg = 0; eg < 4; ++eg) {
            wb[eg * 2 + 0] = *(const uint4*)&whf[(eg * 64 + ksa) * 512 + l * 8];
            wb[eg * 2 + 1] = *(const uint4*)&wlf[(eg * 64 + ksa) * 512 + l * 8];
        }
        // split-convert A
        ushort h[8], q[8];
        cvt_split(a0.x, h[0], q[0]); cvt_split(a0.y, h[1], q[1]);
        cvt_split(a0.z, h[2], q[2]); cvt_split(a0.w, h[3], q[3]);
        cvt_split(a1.x, h[4], q[4]); cvt_split(a1.y, h[5], q[5]);
        cvt_split(a1.z, h[6], q[6]); cvt_split(a1.w, h[7], q[7]);
        uint4 hv = {(uint)h[0] | ((uint)h[1] << 16), (uint)h[2] | ((uint)h[3] << 16),
                    (uint)h[4] | ((uint)h[5] << 16), (uint)h[6] | ((uint)h[7] << 16)};
        uint4 qv = {(uint)q[0] | ((uint)q[1] << 16), (uint)q[2] | ((uint)q[3] << 16),
                    (uint)q[4] | ((uint)q[5] << 16), (uint)q[6] | ((uint)q[7] << 16)};
        bf16x8 ah = __builtin_bit_cast(bf16x8, hv);
        bf16x8 al = __builtin_bit_cast(bf16x8, qv);
#pragma unroll
        for (int eg = 0; eg < 4; ++eg) {
            bf16x8 bh = __builtin_bit_cast(bf16x8, wb[eg * 2 + 0]);
            bf16x8 bl = __builtin_bit_cast(bf16x8, wb[eg * 2 + 1]);
            acc[eg] = __builtin_amdgcn_mfma_f32_16x16x32_bf16(ah, bh, acc[eg], 0, 0, 0);
            acc[eg] = __builtin_amdgcn_mfma_f32_16x16x32_bf16(al, bh, acc[eg], 0, 0, 0);
            acc[eg] = __builtin_amdgcn_mfma_f32_16x16x32_bf16(ah, bl, acc[eg], 0, 0, 0);
        }
    }

    // ---- partials to LDS; the ONLY barrier ----
#pragma unroll
    for (int eg = 0; eg < 4; ++eg)
#pragma unroll
    for (int r = 0; r < 4; ++r)
        part[wv][kg * 4 + r][eg * 16 + tr] = acc[eg][r];
    __syncthreads();

    // ---- 4-way K-reduce + softmax/top-2 (wave wv: tokens wv*4..wv*4+3) ----
    const int e = l;
    const float be = b[e];
    for (int ti = 0; ti < 4; ++ti) {
        const int t = wv * 4 + ti;
        float logit = part[0][t][e] + part[1][t][e]
                    + part[2][t][e] + part[3][t][e] + be;

        float v1, v2, v3; int i1, i2;
        for (int pass = 0; pass < 2; ++pass) {
            v1 = logit; i1 = e;
#pragma unroll
            for (int off = 32; off >= 1; off >>= 1) {
                float ov = __shfl_xor(v1, off, 64);
                int   oi = __shfl_xor(i1, off, 64);
                if (ov > v1 || (ov == v1 && oi < i1)) { v1 = ov; i1 = oi; }
            }
            v2 = (e == i1) ? -3.4e38f : logit;
            i2 = (e == i1) ? N_EXP : e;
#pragma unroll
            for (int off = 32; off >= 1; off >>= 1) {
                float ov = __shfl_xor(v2, off, 64);
                int   oi = __shfl_xor(i2, off, 64);
                if (ov > v2 || (ov == v2 && oi < i2)) { v2 = ov; i2 = oi; }
            }
            v3 = (e == i1 || e == i2) ? -3.4e38f : logit;
#pragma unroll
            for (int off = 32; off >= 1; off >>= 1) {
                float ov = __shfl_xor(v3, off, 64);
                v3 = (ov > v3) ? ov : v3;
            }
            if (pass == 1) break;
            const bool risky = (v1 - v2 < DELTA) || (v2 - v3 < DELTA);
            if (!risky) break;
            // exact fp32 recompute of candidate experts (wave-uniform path)
            unsigned long long cm = __ballot(logit >= v2 - DELTA2);
            const float* xr = x + (size_t)(t0 + t) * C_IN;
            while (cm) {
                const int ce = __ffsll((unsigned long long)cm) - 1;
                cm &= cm - 1;
                const float* wr = Wf + (size_t)ce * C_IN;
                float p = 0.f;
#pragma unroll 8
                for (int i = 0; i < 32; ++i)
                    p = fmaf(xr[l + 64 * i], wr[l + 64 * i], p);
#pragma unroll
                for (int off = 32; off >= 1; off >>= 1)
                    p += __shfl_xor(p, off, 64);
                if (e == ce) logit = p + be;
            }
        }

        float ex = expf(logit - v1);
        float ssum = ex;
#pragma unroll
        for (int off = 32; off >= 1; off >>= 1)
            ssum += __shfl_xor(ssum, off, 64);
        const float inv = 1.0f / ssum;
        const float p1 = inv;
        const float p2 = expf(v2 - v1) * inv;
        const float o = (e == i1) ? p1 : ((e == i2) ? p2 : 0.0f);
        out[(size_t)(t0 + t) * N_EXP + e] = o;
    }
}

extern "C" void kernel_launch(void* const* d_in, const int* in_sizes, int n_in,
                              void* d_out, int out_size, void* d_ws, size_t ws_size,
                              hipStream_t stream) {
    const float* x = (const float*)d_in[0];   // [4,4096,2048]
    const float* W = (const float*)d_in[1];   // [64,2048]
    const float* b = (const float*)d_in[2];   // [64]
    float* out = (float*)d_out;               // [4,4096,64]

    ushort* whf = (ushort*)d_ws;              // frag-major bf16 hi, 256 KB
    ushort* wlf = whf + N_EXP * C_IN;         // frag-major bf16 lo, 256 KB

    conv_w_kernel<<<512, 256, 0, stream>>>(W, whf, wlf);

    const int tokens = in_sizes[0] / C_IN;    // 16384
    const int grid = tokens / TPB;            // 1024
    topk_gate_kernel<<<grid, 256, 0, stream>>>(x, W, b, whf, wlf, out);
}

// Round 7
// 54.592 us; speedup vs baseline: 1.6402x; 1.0344x over previous
//
#include <hip/hip_runtime.h>
#include <math.h>

#define C_IN 2048
#define N_EXP 64
#define TPB 32            // tokens per block (all 4 waves compute all 32)
#define KSTEPS 16         // per-wave ksteps (K-window 512 = 16 x 32)
#define DELTA  3e-4f      // risky-gap threshold (>=100x expected logit error)
#define DELTA2 1e-3f      // candidate window around v2

typedef __bf16 bf16x8 __attribute__((ext_vector_type(8)));
typedef float f32x4 __attribute__((ext_vector_type(4)));

__device__ __forceinline__ void cvt_split(float f, ushort& h, ushort& l) {
    uint u = __float_as_uint(f);
    uint hr = (u + (0x7FFFu + ((u >> 16) & 1u))) >> 16;
    h = (ushort)hr;
    float hf = __uint_as_float(hr << 16);
    uint v = __float_as_uint(f - hf);
    l = (ushort)((v + (0x7FFFu + ((v >> 16) & 1u))) >> 16);
}

// W [64][2048] fp32 -> frag-major bf16 hi/lo (256 KB each):
// o = (eg*64 + ksa)*512 + lane*8 + j  <->  e = eg*16+(lane&15), k = ksa*32+(lane>>4)*8+j
// (identical layout to r5/r6 — fragment bytes verified by passing refcheck)
__global__ void conv_w_kernel(const float* __restrict__ W,
                              ushort* __restrict__ whf, ushort* __restrict__ wlf) {
    const int o = blockIdx.x * 256 + threadIdx.x;   // 0..131071
    const int egks = o >> 9;
    const int lane = (o >> 3) & 63;
    const int j = o & 7;
    const int e = (egks >> 6) * 16 + (lane & 15);
    const int k = (egks & 63) * 32 + (lane >> 4) * 8 + j;
    ushort h, lo;
    cvt_split(W[e * C_IN + k], h, lo);
    whf[o] = h;
    wlf[o] = lo;
}

// async global->LDS, 16 B per lane (linear dest = wave base + lane*16)
__device__ __forceinline__ void gload16(const ushort* g, ushort* l) {
    __builtin_amdgcn_global_load_lds(
        (const __attribute__((address_space(1))) uint32_t*)g,
        (__attribute__((address_space(3))) uint32_t*)l, 16, 0, 0);
}

// Main: 512 blocks x 256 thr (4 waves) = 2 blocks/CU. ZERO barriers in the
// hot loop. Wave w: 32 tokens (M=32, 2 A-frags) x 64 experts x K-quarter
// [w*512, w*512+512). W bf16 hi/lo staged per-wave-private via ASYNC
// global_load_lds (8 x 1KB per kstep, double-buffered; no VGPR cost, deep
// queue), paced by counted s_waitcnt vmcnt(12) — never drained mid-loop.
// x read direct global->reg, 1 kstep ahead (compiler-tracked waits).
// Per kstep: 8 gload_lds + 4 x-loads + 8 ds_read_b128 + 16 cvt_split +
// 24 MFMA (split-bf16: xh*wh + xl*wh + xh*wl). Epilogue: partials into own
// LDS region, ONE __syncthreads, 4-way K-reduce + softmax/top-2 + exact
// fp32 repair for near-tie tokens.
__global__ __launch_bounds__(256, 2) void topk_gate_kernel(
    const float* __restrict__ x, const float* __restrict__ Wf,
    const float* __restrict__ b, const ushort* __restrict__ whf,
    const ushort* __restrict__ wlf, float* __restrict__ out)
{
    __shared__ __align__(16) ushort smem[32768];   // 64 KB = 4 waves x 16 KB

    const int tid = threadIdx.x;
    const int w = tid >> 6, l = tid & 63;
    const int t0 = blockIdx.x * TPB;
    const int tr = l & 15;        // A-frag token row (low 16)
    const int kg = l >> 4;        // k-group 0..3

    ushort* wbase = smem + w * 8192;   // this wave's private 16 KB (2 bufs x 8 KB)

    const float* xg = x + (size_t)t0 * C_IN + w * (KSTEPS * 32) + kg * 8;

    f32x4 acc[2][4];
#pragma unroll
    for (int mf = 0; mf < 2; ++mf)
#pragma unroll
    for (int eg = 0; eg < 4; ++eg) acc[mf][eg] = (f32x4){0.f, 0.f, 0.f, 0.f};

    // ---- staging / load helpers (per-wave private, async) ----
#define WSTAGE(I) do {                                                        \
    const int ksa_ = w * KSTEPS + (I);                                        \
    ushort* dst_ = wbase + ((I) & 1) * 4096;                                  \
    _Pragma("unroll") for (int eg_ = 0; eg_ < 4; ++eg_) {                     \
        gload16(whf + (size_t)(eg_ * 64 + ksa_) * 512 + l * 8,                \
                dst_ + (eg_ * 2 + 0) * 512 + l * 8);                          \
        gload16(wlf + (size_t)(eg_ * 64 + ksa_) * 512 + l * 8,                \
                dst_ + (eg_ * 2 + 1) * 512 + l * 8);                          \
    } } while (0)

#define XLOAD(DST, I) do {                                                    \
    (DST)[0] = *(const float4*)(xg + (size_t)tr * C_IN + (I) * 32);           \
    (DST)[1] = *(const float4*)(xg + (size_t)tr * C_IN + (I) * 32 + 4);       \
    (DST)[2] = *(const float4*)(xg + (size_t)(tr + 16) * C_IN + (I) * 32);    \
    (DST)[3] = *(const float4*)(xg + (size_t)(tr + 16) * C_IN + (I) * 32 + 4);\
    } while (0)

    float4 xb[2][4];
    WSTAGE(0);
    XLOAD(xb[0], 0);

#pragma unroll
    for (int i = 0; i < KSTEPS; ++i) {
        if (i + 1 < KSTEPS) {
            WSTAGE(i + 1);                 // async, no VGPR
            XLOAD(xb[(i + 1) & 1], i + 1); // reg prefetch, compiler-tracked
            asm volatile("s_waitcnt vmcnt(12)" ::: "memory");  // chunk i landed
        } else {
            asm volatile("s_waitcnt vmcnt(0)" ::: "memory");
        }
        __builtin_amdgcn_sched_barrier(0);

        // B-frags from LDS (exact byte layout of r6's verified global frags)
        const ushort* tb = wbase + (i & 1) * 4096;
        uint4 bfr[8];
#pragma unroll
        for (int eg = 0; eg < 4; ++eg) {
            bfr[eg * 2 + 0] = *(const uint4*)&tb[(eg * 2 + 0) * 512 + l * 8];
            bfr[eg * 2 + 1] = *(const uint4*)&tb[(eg * 2 + 1) * 512 + l * 8];
        }

        // A-frags: split-convert this kstep's x
        const float4* xc = xb[i & 1];
        ushort h[16], q[16];
        cvt_split(xc[0].x, h[0], q[0]); cvt_split(xc[0].y, h[1], q[1]);
        cvt_split(xc[0].z, h[2], q[2]); cvt_split(xc[0].w, h[3], q[3]);
        cvt_split(xc[1].x, h[4], q[4]); cvt_split(xc[1].y, h[5], q[5]);
        cvt_split(xc[1].z, h[6], q[6]); cvt_split(xc[1].w, h[7], q[7]);
        cvt_split(xc[2].x, h[8], q[8]); cvt_split(xc[2].y, h[9], q[9]);
        cvt_split(xc[2].z, h[10], q[10]); cvt_split(xc[2].w, h[11], q[11]);
        cvt_split(xc[3].x, h[12], q[12]); cvt_split(xc[3].y, h[13], q[13]);
        cvt_split(xc[3].z, h[14], q[14]); cvt_split(xc[3].w, h[15], q[15]);
        uint4 h0 = {(uint)h[0] | ((uint)h[1] << 16), (uint)h[2] | ((uint)h[3] << 16),
                    (uint)h[4] | ((uint)h[5] << 16), (uint)h[6] | ((uint)h[7] << 16)};
        uint4 q0 = {(uint)q[0] | ((uint)q[1] << 16), (uint)q[2] | ((uint)q[3] << 16),
                    (uint)q[4] | ((uint)q[5] << 16), (uint)q[6] | ((uint)q[7] << 16)};
        uint4 h1 = {(uint)h[8] | ((uint)h[9] << 16), (uint)h[10] | ((uint)h[11] << 16),
                    (uint)h[12] | ((uint)h[13] << 16), (uint)h[14] | ((uint)h[15] << 16)};
        uint4 q1 = {(uint)q[8] | ((uint)q[9] << 16), (uint)q[10] | ((uint)q[11] << 16),
                    (uint)q[12] | ((uint)q[13] << 16), (uint)q[14] | ((uint)q[15] << 16)};
        bf16x8 ah0 = __builtin_bit_cast(bf16x8, h0);
        bf16x8 al0 = __builtin_bit_cast(bf16x8, q0);
        bf16x8 ah1 = __builtin_bit_cast(bf16x8, h1);
        bf16x8 al1 = __builtin_bit_cast(bf16x8, q1);

        __builtin_amdgcn_s_setprio(1);
#pragma unroll
        for (int eg = 0; eg < 4; ++eg) {
            bf16x8 bh = __builtin_bit_cast(bf16x8, bfr[eg * 2 + 0]);
            bf16x8 bl = __builtin_bit_cast(bf16x8, bfr[eg * 2 + 1]);
            acc[0][eg] = __builtin_amdgcn_mfma_f32_16x16x32_bf16(ah0, bh, acc[0][eg], 0, 0, 0);
            acc[1][eg] = __builtin_amdgcn_mfma_f32_16x16x32_bf16(ah1, bh, acc[1][eg], 0, 0, 0);
            acc[0][eg] = __builtin_amdgcn_mfma_f32_16x16x32_bf16(al0, bh, acc[0][eg], 0, 0, 0);
            acc[1][eg] = __builtin_amdgcn_mfma_f32_16x16x32_bf16(al1, bh, acc[1][eg], 0, 0, 0);
            acc[0][eg] = __builtin_amdgcn_mfma_f32_16x16x32_bf16(ah0, bl, acc[0][eg], 0, 0, 0);
            acc[1][eg] = __builtin_amdgcn_mfma_f32_16x16x32_bf16(ah1, bl, acc[1][eg], 0, 0, 0);
        }
        __builtin_amdgcn_s_setprio(0);
    }

    // ---- partials into OWN region (drained; no other wave touches it) ----
    float* pw = (float*)wbase;   // [32 tokens][64 experts] = 8 KB
#pragma unroll
    for (int mf = 0; mf < 2; ++mf)
#pragma unroll
    for (int eg = 0; eg < 4; ++eg)
#pragma unroll
    for (int r = 0; r < 4; ++r)
        pw[(mf * 16 + kg * 4 + r) * 64 + eg * 16 + tr] = acc[mf][eg][r];

    __syncthreads();   // the ONLY barrier

    // ---- 4-way K-reduce + softmax/top-2 (wave w: tokens w*8..w*8+7) ----
    const float* fp = (const float*)smem;   // wave w2 partials at w2*4096 floats
    const int e = l;
    const float be = b[e];
    for (int ti = 0; ti < 8; ++ti) {
        const int t = w * 8 + ti;
        float logit = fp[0 * 4096 + t * 64 + e] + fp[1 * 4096 + t * 64 + e]
                    + fp[2 * 4096 + t * 64 + e] + fp[3 * 4096 + t * 64 + e] + be;

        float v1, v2, v3; int i1, i2;
        for (int pass = 0; pass < 2; ++pass) {
            v1 = logit; i1 = e;
#pragma unroll
            for (int off = 32; off >= 1; off >>= 1) {
                float ov = __shfl_xor(v1, off, 64);
                int   oi = __shfl_xor(i1, off, 64);
                if (ov > v1 || (ov == v1 && oi < i1)) { v1 = ov; i1 = oi; }
            }
            v2 = (e == i1) ? -3.4e38f : logit;
            i2 = (e == i1) ? N_EXP : e;
#pragma unroll
            for (int off = 32; off >= 1; off >>= 1) {
                float ov = __shfl_xor(v2, off, 64);
                int   oi = __shfl_xor(i2, off, 64);
                if (ov > v2 || (ov == v2 && oi < i2)) { v2 = ov; i2 = oi; }
            }
            v3 = (e == i1 || e == i2) ? -3.4e38f : logit;
#pragma unroll
            for (int off = 32; off >= 1; off >>= 1) {
                float ov = __shfl_xor(v3, off, 64);
                v3 = (ov > v3) ? ov : v3;
            }
            if (pass == 1) break;
            const bool risky = (v1 - v2 < DELTA) || (v2 - v3 < DELTA);
            if (!risky) break;
            // exact fp32 recompute of candidate experts (wave-uniform path)
            unsigned long long cm = __ballot(logit >= v2 - DELTA2);
            const float* xr = x + (size_t)(t0 + t) * C_IN;
            while (cm) {
                const int ce = __ffsll((unsigned long long)cm) - 1;
                cm &= cm - 1;
                const float* wr = Wf + (size_t)ce * C_IN;
                float p = 0.f;
#pragma unroll 8
                for (int i = 0; i < 32; ++i)
                    p = fmaf(xr[l + 64 * i], wr[l + 64 * i], p);
#pragma unroll
                for (int off = 32; off >= 1; off >>= 1)
                    p += __shfl_xor(p, off, 64);
                if (e == ce) logit = p + be;
            }
        }

        float ex = expf(logit - v1);
        float ssum = ex;
#pragma unroll
        for (int off = 32; off >= 1; off >>= 1)
            ssum += __shfl_xor(ssum, off, 64);
        const float inv = 1.0f / ssum;
        const float p1 = inv;
        const float p2 = expf(v2 - v1) * inv;
        const float o = (e == i1) ? p1 : ((e == i2) ? p2 : 0.0f);
        out[(size_t)(t0 + t) * N_EXP + e] = o;
    }
#undef WSTAGE
#undef XLOAD
}

extern "C" void kernel_launch(void* const* d_in, const int* in_sizes, int n_in,
                              void* d_out, int out_size, void* d_ws, size_t ws_size,
                              hipStream_t stream) {
    const float* x = (const float*)d_in[0];   // [4,4096,2048]
    const float* W = (const float*)d_in[1];   // [64,2048]
    const float* b = (const float*)d_in[2];   // [64]
    float* out = (float*)d_out;               // [4,4096,64]

    ushort* whf = (ushort*)d_ws;              // frag-major bf16 hi, 256 KB
    ushort* wlf = whf + N_EXP * C_IN;         // frag-major bf16 lo, 256 KB

    conv_w_kernel<<<512, 256, 0, stream>>>(W, whf, wlf);

    const int tokens = in_sizes[0] / C_IN;    // 16384
    const int grid = tokens / TPB;            // 512
    topk_gate_kernel<<<grid, 256, 0, stream>>>(x, W, b, whf, wlf, out);
}